// Round 17
// baseline (62.815 us; speedup 1.0000x reference)
//
#include <hip/hip_runtime.h>
#include <hip/hip_bf16.h>
#include <stdint.h>

#define BROWS 16384
#define DIM   256
#define BM    128               // A rows per block (persistent in registers)
#define NBM   (BROWS / BM)      // 128 row blocks
#define NBNR  16                // col-range blocks; each covers 1024 cols
#define NHALF 16                // 64-col half-tiles per block
#define NCHUNK 16               // per-row partial chunks (16 bnr)

#define LOG2E 1.44269504088896340736f

typedef __attribute__((ext_vector_type(8))) int  i32x8;
typedef __attribute__((ext_vector_type(4))) float f32x4;
typedef unsigned char uchar;

#if __has_builtin(__builtin_amdgcn_exp2f)
#define EXP2(x) __builtin_amdgcn_exp2f(x)   // bare v_exp_f32; |arg| small -> exact
#else
#define EXP2(x) exp2f(x)
#endif

__device__ __forceinline__ void gload_lds16(const void* g, void* l) {
  __builtin_amdgcn_global_load_lds(
      (const __attribute__((address_space(1))) void*)g,
      (__attribute__((address_space(3))) void*)l, 16, 0, 0);
}

// e2m1 RTN: grid {0,.5,1,1.5,2,3,4,6}, monotonic enc 0..7, sign = bit3.
__device__ __forceinline__ unsigned q4(float x) {
  float a = fabsf(x);
  unsigned q = (a >= 0.25f) + (a >= 0.75f) + (a >= 1.25f) + (a >= 1.75f) +
               (a >= 2.5f) + (a >= 3.5f) + (a >= 5.0f);
  return q | ((__float_as_uint(x) >> 28) & 8u);
}

// Tiled fp4 layout ("frag-major", r16-verified): row r, 32-elem K-chunk c 0..7:
//   byte addr = (r>>4)*2048 + c*256 + (r&15)*16 + b(0..15)
// Wave frag (lane l: row 16g+(l&15), K-chunk kt*4+(l>>4)) = g*2048 + kt*1024
// + l*16 -> 1KB contiguous per frag. Within-K nibble order is a permutation
// applied identically to A and B -> cancels in the dot product.

// ---------------- Kernel A: normalize BOTH matrices -> tiled fp4 + diag -----
// A = e2m1(x_hat * 16 * log2e), B = e2m1(x_hat * 16); MFMA E8M0 scales
// (2^-4 per side) undo the 16*16. dlog exact f32.
__global__ void normalize_both(const float* __restrict__ o,
                               const float* __restrict__ t,
                               uchar* __restrict__ o4,
                               uchar* __restrict__ t4,
                               float* __restrict__ dlog) {
  int row  = blockIdx.x * 4 + (threadIdx.x >> 6);
  int lane = threadIdx.x & 63;
  float4 a = *(reinterpret_cast<const float4*>(o + (size_t)row * DIM) + lane);
  float4 b = *(reinterpret_cast<const float4*>(t + (size_t)row * DIM) + lane);
  float sso = a.x * a.x + a.y * a.y + a.z * a.z + a.w * a.w;
  float sst = b.x * b.x + b.y * b.y + b.z * b.z + b.w * b.w;
  float d   = a.x * b.x + a.y * b.y + a.z * b.z + a.w * b.w;
#pragma unroll
  for (int m = 1; m < 64; m <<= 1) {
    sso += __shfl_xor(sso, m);
    sst += __shfl_xor(sst, m);
    d   += __shfl_xor(d, m);
  }
  float ro = rsqrtf(sso);
  float rt = rsqrtf(sst);
  if (lane == 0) dlog[row] = d * ro * rt;
  float qo = ro * (16.0f * LOG2E);   // A carries log2e
  float qt = rt * 16.0f;
  unsigned wo = q4(a.x * qo) | (q4(a.y * qo) << 4) |
                (q4(a.z * qo) << 8) | (q4(a.w * qo) << 12);
  unsigned wt = q4(b.x * qt) | (q4(b.y * qt) << 4) |
                (q4(b.z * qt) << 8) | (q4(b.w * qt) << 12);
  size_t taddr = (size_t)(row >> 4) * 2048 + (size_t)((lane >> 3) * 256) +
                 (size_t)((row & 15) * 16) + (size_t)((lane & 7) * 2);
  *reinterpret_cast<unsigned short*>(o4 + taddr) = (unsigned short)wo;
  *reinterpret_cast<unsigned short*>(t4 + taddr) = (unsigned short)wt;
}

// ---------------- Kernel B: persistent-A fp4 GEMM, B via half-tile LDS ------
// r16 structure; changes: launch_bounds(256,8) -- r16's 50% occupancy was the
// explicit 5-block bound (VGPR 32, LDS 16KB both allow 8) -- and B-operand
// regs written in-place (lanes 0..3 only) to kill the upper-zero pack movs.
// mfma_scale_16x16x128 cbsz=4 blgp=4 (FP4), E8M0 scales 0x7B = 2^-4.
// Frag: lane l holds row (l&15), K-chunk (l>>4), data in v[0:3].
// C/D: col = lane&15, row = (lane>>4)*4 + reg.
__global__ __launch_bounds__(256, 8) void gemm_expsum(
    const uchar* __restrict__ A4,   // ohat fp4 tiled (x16*log2e)
    const uchar* __restrict__ B4,   // that fp4 tiled (x16)
    float* __restrict__ partial) {
  __shared__ __align__(16) uchar Bs[2][8192];  // 2 x 8 KB

  int b   = blockIdx.x;
  int xcd = b & 7;
  int idx = b >> 3;               // 0..255
  int bm  = xcd * 16 + (idx & 15);
  int bnr = idx >> 4;             // 0..15

  int tid  = threadIdx.x;
  int lane = tid & 63;
  int wid  = tid >> 6;            // 0..3 == wr (32-row strip)

  const uchar* Ap = A4 + (size_t)(bm * 8 + wid * 2) * 2048 + (size_t)lane * 16;
  const uchar* Bg = B4 + (size_t)bnr * 131072;   // 128 KB strip (1024 cols)

  // persistent A fragments: data 4 dwords, padded to 8-dword operands
  i32x8 af[2][2];
#pragma unroll
  for (int m = 0; m < 2; ++m)
#pragma unroll
    for (int kt = 0; kt < 2; ++kt) {
      int4 d = *reinterpret_cast<const int4*>(Ap + m * 2048 + kt * 1024);
      af[m][kt] = (i32x8){d.x, d.y, d.z, d.w, 0, 0, 0, 0};
    }

  float v[8];
#pragma unroll
  for (int j = 0; j < 8; ++j) v[j] = 0.f;

  const f32x4 zero4 = {0.f, 0.f, 0.f, 0.f};
  // B operand regs: allocated once; only lanes 0..3 rewritten per fragment
  // (upper 4 dwords are ignored by the FP4 format -> no re-zeroing movs).
  i32x8 b0 = (i32x8){0, 0, 0, 0, 0, 0, 0, 0};
  i32x8 b1 = (i32x8){0, 0, 0, 0, 0, 0, 0, 0};

  // stage half-tile ht (8KB) into buf s: 2 passes x (256 thr x 16B), LINEAR.
#define STAGE(ht, s)                                                           \
  {                                                                            \
    _Pragma("unroll") for (int p = 0; p < 2; ++p)                              \
        gload_lds16(Bg + (size_t)(ht) * 8192 + p * 4096 + wid * 1024 +         \
                        lane * 16,                                             \
                    (char*)Bs[s] + p * 4096 + wid * 1024);                     \
  }

#define COMPUTE(s)                                                             \
  {                                                                            \
    const uchar* bb = Bs[s];                                                   \
    _Pragma("unroll") for (int n = 0; n < 4; ++n) {                            \
      const uchar* cb = bb + n * 2048 + lane * 16;                             \
      int4 d0 = *reinterpret_cast<const int4*>(cb);                            \
      int4 d1 = *reinterpret_cast<const int4*>(cb + 1024);                     \
      b0[0] = d0.x; b0[1] = d0.y; b0[2] = d0.z; b0[3] = d0.w;                  \
      b1[0] = d1.x; b1[1] = d1.y; b1[2] = d1.z; b1[3] = d1.w;                  \
      _Pragma("unroll") for (int m = 0; m < 2; ++m) {                          \
        f32x4 acc = __builtin_amdgcn_mfma_scale_f32_16x16x128_f8f6f4(          \
            af[m][0], b0, zero4, 4, 4, 0, 0x7B7B7B7B, 0, 0x7B7B7B7B);          \
        acc = __builtin_amdgcn_mfma_scale_f32_16x16x128_f8f6f4(                \
            af[m][1], b1, acc, 4, 4, 0, 0x7B7B7B7B, 0, 0x7B7B7B7B);            \
        v[m * 4 + 0] += EXP2(acc[0]);                                          \
        v[m * 4 + 1] += EXP2(acc[1]);                                          \
        v[m * 4 + 2] += EXP2(acc[2]);                                          \
        v[m * 4 + 3] += EXP2(acc[3]);                                          \
      }                                                                        \
    }                                                                          \
  }

  STAGE(0, 0);
  __syncthreads();                 // half-tile 0 resident
#pragma unroll
  for (int ht = 0; ht < NHALF; ++ht) {
    if (ht < NHALF - 1) STAGE(ht + 1, (ht + 1) & 1);  // async into other buffer
    COMPUTE(ht & 1);
    if (ht < NHALF - 1) __syncthreads();  // drain stage(ht+1); readers of ht done
  }
#undef STAGE
#undef COMPUTE

  // ---- bisect butterfly: v[8] over the 16 fragment columns (r12-verified) ----
#pragma unroll
  for (int s = 0; s < 3; ++s) {
    const int len = 8 >> s;
    const int bit = (lane >> s) & 1;
#pragma unroll
    for (int t = 0; t < 4; ++t) {
      if (t < (len >> 1)) {
        float a = v[2 * t], b2 = v[2 * t + 1];
        float recv = __shfl_xor(bit ? a : b2, 1 << s);
        v[t] = (bit ? b2 : a) + recv;
      }
    }
  }
  v[0] += __shfl_xor(v[0], 8);   // complete the 16-lane column sum
  if ((lane & 8) == 0) {
    int j   = lane & 7;          // m = j>>2, r = j&3
    int sub = lane >> 4;         // 0..3
    int row = bm * BM + wid * 32 + (j >> 2) * 16 + sub * 4 + (j & 3);
    partial[(size_t)row * NCHUNK + bnr] = v[0];
  }
}

// ---------------- Kernel C: per-row finish: log(sum) - exact diag ----------
__global__ void row_finish(const float* __restrict__ partial,
                           const float* __restrict__ dlog,
                           float* __restrict__ rowloss) {
  int row = blockIdx.x * 256 + threadIdx.x;
  const float4* p = reinterpret_cast<const float4*>(partial + (size_t)row * NCHUNK);
  float4 p0 = p[0], p1 = p[1], p2 = p[2], p3 = p[3];
  float s = (p0.x + p0.y + p0.z + p0.w) + (p1.x + p1.y + p1.z + p1.w) +
            (p2.x + p2.y + p2.z + p2.w) + (p3.x + p3.y + p3.z + p3.w);
  rowloss[row] = logf(s) - dlog[row];
}

// ---------------- Kernel D: mean over rows -> d_out[0] ----------------
__global__ void final_reduce(const float* __restrict__ rl, float* __restrict__ out) {
  __shared__ float sm[16];
  float s = 0.f;
  for (int i = threadIdx.x; i < BROWS; i += 1024) s += rl[i];
#pragma unroll
  for (int m = 1; m < 64; m <<= 1) s += __shfl_xor(s, m);
  int wid = threadIdx.x >> 6, lane = threadIdx.x & 63;
  if (lane == 0) sm[wid] = s;
  __syncthreads();
  if (wid == 0) {
    float v = (lane < 16) ? sm[lane] : 0.f;
#pragma unroll
    for (int m = 1; m < 16; m <<= 1) v += __shfl_xor(v, m);
    if (lane == 0) out[0] = v / (float)BROWS;
  }
}

extern "C" void kernel_launch(void* const* d_in, const int* in_sizes, int n_in,
                              void* d_out, int out_size, void* d_ws, size_t ws_size,
                              hipStream_t stream) {
  const float* outputs = (const float*)d_in[0];
  const float* targets = (const float*)d_in[1];
  float* out = (float*)d_out;
  char* ws = (char*)d_ws;

  uchar* o4      = (uchar*)ws;                                      // 2 MB (tiled fp4)
  uchar* t4      = (uchar*)(ws + (size_t)2 * 1024 * 1024);          // 2 MB (tiled fp4)
  float* partial = (float*)(ws + (size_t)4 * 1024 * 1024);          // 1 MB
  float* dlog    = (float*)(ws + (size_t)6 * 1024 * 1024);          // 64 KB
  float* rowloss = (float*)(ws + (size_t)6 * 1024 * 1024 + 65536);  // 64 KB

  normalize_both<<<BROWS / 4, 256, 0, stream>>>(outputs, targets, o4, t4, dlog);
  gemm_expsum<<<NBM * NBNR, 256, 0, stream>>>(o4, t4, partial);
  row_finish<<<BROWS / 256, 256, 0, stream>>>(partial, dlog, rowloss);
  final_reduce<<<1, 1024, 0, stream>>>(rowloss, out);
}

// Round 18
// 62.644 us; speedup vs baseline: 1.0027x; 1.0027x over previous
//
#include <hip/hip_runtime.h>
#include <hip/hip_bf16.h>
#include <stdint.h>

#define BROWS 16384
#define DIM   256
#define BM    128               // A rows per block
#define NBM   (BROWS / BM)      // 128 row blocks
#define NBNR  16                // col-range blocks; each covers 1024 cols
#define NHALF 16                // 64-col half-tiles per block
#define NCHUNK 32               // per-row partial chunks (16 bnr x 2 wch)

#define LOG2E 1.44269504088896340736f

typedef __attribute__((ext_vector_type(8))) int  i32x8;
typedef __attribute__((ext_vector_type(4))) float f32x4;
typedef unsigned char uchar;

#if __has_builtin(__builtin_amdgcn_exp2f)
#define EXP2(x) __builtin_amdgcn_exp2f(x)   // bare v_exp_f32; |arg| small -> exact
#else
#define EXP2(x) exp2f(x)
#endif

__device__ __forceinline__ void gload_lds16(const void* g, void* l) {
  __builtin_amdgcn_global_load_lds(
      (const __attribute__((address_space(1))) void*)g,
      (__attribute__((address_space(3))) void*)l, 16, 0, 0);
}

// e2m1 RTN: grid {0,.5,1,1.5,2,3,4,6}, monotonic enc 0..7, sign = bit3.
__device__ __forceinline__ unsigned q4(float x) {
  float a = fabsf(x);
  unsigned q = (a >= 0.25f) + (a >= 0.75f) + (a >= 1.25f) + (a >= 1.75f) +
               (a >= 2.5f) + (a >= 3.5f) + (a >= 5.0f);
  return q | ((__float_as_uint(x) >> 28) & 8u);
}

// Tiled fp4 layout ("frag-major", r16/r17-verified): row r, 32-elem K-chunk c:
//   byte addr = (r>>4)*2048 + c*256 + (r&15)*16 + b(0..15)
// Wave frag (lane l: row 16g+(l&15), K-chunk kt*4+(l>>4)) = g*2048 + kt*1024
// + l*16 -> 1KB contiguous per frag.

// ---------------- Kernel A: normalize BOTH matrices -> tiled fp4 + diag -----
__global__ void normalize_both(const float* __restrict__ o,
                               const float* __restrict__ t,
                               uchar* __restrict__ o4,
                               uchar* __restrict__ t4,
                               float* __restrict__ dlog) {
  int row  = blockIdx.x * 4 + (threadIdx.x >> 6);
  int lane = threadIdx.x & 63;
  float4 a = *(reinterpret_cast<const float4*>(o + (size_t)row * DIM) + lane);
  float4 b = *(reinterpret_cast<const float4*>(t + (size_t)row * DIM) + lane);
  float sso = a.x * a.x + a.y * a.y + a.z * a.z + a.w * a.w;
  float sst = b.x * b.x + b.y * b.y + b.z * b.z + b.w * b.w;
  float d   = a.x * b.x + a.y * b.y + a.z * b.z + a.w * b.w;
#pragma unroll
  for (int m = 1; m < 64; m <<= 1) {
    sso += __shfl_xor(sso, m);
    sst += __shfl_xor(sst, m);
    d   += __shfl_xor(d, m);
  }
  float ro = rsqrtf(sso);
  float rt = rsqrtf(sst);
  if (lane == 0) dlog[row] = d * ro * rt;
  float qo = ro * (16.0f * LOG2E);   // A carries log2e
  float qt = rt * 16.0f;
  unsigned wo = q4(a.x * qo) | (q4(a.y * qo) << 4) |
                (q4(a.z * qo) << 8) | (q4(a.w * qo) << 12);
  unsigned wt = q4(b.x * qt) | (q4(b.y * qt) << 4) |
                (q4(b.z * qt) << 8) | (q4(b.w * qt) << 12);
  size_t taddr = (size_t)(row >> 4) * 2048 + (size_t)((lane >> 3) * 256) +
                 (size_t)((row & 15) * 16) + (size_t)((lane & 7) * 2);
  *reinterpret_cast<unsigned short*>(o4 + taddr) = (unsigned short)wo;
  *reinterpret_cast<unsigned short*>(t4 + taddr) = (unsigned short)wt;
}

// ---------------- Kernel B: persistent-A fp4 GEMM, B via half-tile LDS ------
// 512 threads = 8 waves: wr = wid&3 (32-row strip), wch = wid>>2 (32-col half
// of the 64-col half-tile). 16 KB LDS/block; 4 blocks x 8 waves = 32 waves/CU
// even under the observed ~4-block residency cap (r15/r17 post-mortems).
// VGPR budget <= 64 (8 waves/SIMD): af 32 + single B buffer 8 + v 8 + acc 8.
// mfma_scale_16x16x128 FP4 (cbsz=4, blgp=4), E8M0 scales 0x7B = 2^-4.
// Frag: lane l holds row (l&15), K-chunk (l>>4), data in dwords 0..3.
// C/D: col = lane&15, row = (lane>>4)*4 + reg.
__global__ __launch_bounds__(512, 8) void gemm_expsum(
    const uchar* __restrict__ A4,   // ohat fp4 tiled (x16*log2e)
    const uchar* __restrict__ B4,   // that fp4 tiled (x16)
    float* __restrict__ partial) {
  __shared__ __align__(16) uchar Bs[2][8192];  // 2 x 8 KB

  int b   = blockIdx.x;
  int xcd = b & 7;
  int idx = b >> 3;               // 0..255
  int bm  = xcd * 16 + (idx & 15);
  int bnr = idx >> 4;             // 0..15

  int tid  = threadIdx.x;
  int lane = tid & 63;
  int wid  = tid >> 6;            // 0..7
  int wr   = wid & 3;             // 32-row strip
  int wch  = wid >> 2;            // 32-col half

  const uchar* Ap = A4 + (size_t)(bm * 8 + wr * 2) * 2048 + (size_t)lane * 16;
  const uchar* Bg = B4 + (size_t)bnr * 131072;   // 128 KB strip (1024 cols)

  // persistent A fragments: data 4 dwords, upper 4 ignored for FP4
  i32x8 af[2][2];
#pragma unroll
  for (int m = 0; m < 2; ++m)
#pragma unroll
    for (int kt = 0; kt < 2; ++kt) {
      int4 d = *reinterpret_cast<const int4*>(Ap + m * 2048 + kt * 1024);
      af[m][kt] = (i32x8){d.x, d.y, d.z, d.w, 0, 0, 0, 0};
    }

  float v[8];
#pragma unroll
  for (int j = 0; j < 8; ++j) v[j] = 0.f;

  const f32x4 zero4 = {0.f, 0.f, 0.f, 0.f};
  // single B operand buffer, reused across kt (WAR resolved at issue order)
  i32x8 bop = (i32x8){0, 0, 0, 0, 0, 0, 0, 0};

  // stage half-tile ht (8KB): one 16B gload per thread, linear both sides.
#define STAGE(ht, s)                                                           \
  gload_lds16(Bg + (size_t)(ht) * 8192 + wid * 1024 + lane * 16,               \
              (char*)Bs[s] + wid * 1024 + lane * 16);

#define COMPUTE(s)                                                             \
  {                                                                            \
    const uchar* bb = Bs[s];                                                   \
    _Pragma("unroll") for (int nn = 0; nn < 2; ++nn) {                         \
      const uchar* cb = bb + (wch * 2 + nn) * 2048 + lane * 16;                \
      int4 d0 = *reinterpret_cast<const int4*>(cb);                            \
      bop[0] = d0.x; bop[1] = d0.y; bop[2] = d0.z; bop[3] = d0.w;              \
      f32x4 a0 = __builtin_amdgcn_mfma_scale_f32_16x16x128_f8f6f4(             \
          af[0][0], bop, zero4, 4, 4, 0, 0x7B7B7B7B, 0, 0x7B7B7B7B);           \
      f32x4 a1 = __builtin_amdgcn_mfma_scale_f32_16x16x128_f8f6f4(             \
          af[1][0], bop, zero4, 4, 4, 0, 0x7B7B7B7B, 0, 0x7B7B7B7B);           \
      int4 d1 = *reinterpret_cast<const int4*>(cb + 1024);                     \
      bop[0] = d1.x; bop[1] = d1.y; bop[2] = d1.z; bop[3] = d1.w;              \
      a0 = __builtin_amdgcn_mfma_scale_f32_16x16x128_f8f6f4(                   \
          af[0][1], bop, a0, 4, 4, 0, 0x7B7B7B7B, 0, 0x7B7B7B7B);              \
      a1 = __builtin_amdgcn_mfma_scale_f32_16x16x128_f8f6f4(                   \
          af[1][1], bop, a1, 4, 4, 0, 0x7B7B7B7B, 0, 0x7B7B7B7B);              \
      v[0] += EXP2(a0[0]); v[1] += EXP2(a0[1]);                                \
      v[2] += EXP2(a0[2]); v[3] += EXP2(a0[3]);                                \
      v[4] += EXP2(a1[0]); v[5] += EXP2(a1[1]);                                \
      v[6] += EXP2(a1[2]); v[7] += EXP2(a1[3]);                                \
    }                                                                          \
  }

  STAGE(0, 0);
  __syncthreads();                 // half-tile 0 resident
#pragma unroll
  for (int ht = 0; ht < NHALF; ++ht) {
    if (ht < NHALF - 1) STAGE(ht + 1, (ht + 1) & 1);  // async into other buffer
    COMPUTE(ht & 1);
    if (ht < NHALF - 1) __syncthreads();  // drain stage(ht+1); readers of ht done
  }
#undef STAGE
#undef COMPUTE

  // ---- bisect butterfly: v[8] over the 16 fragment columns (r12-verified) ----
#pragma unroll
  for (int s = 0; s < 3; ++s) {
    const int len = 8 >> s;
    const int bit = (lane >> s) & 1;
#pragma unroll
    for (int t = 0; t < 4; ++t) {
      if (t < (len >> 1)) {
        float a = v[2 * t], b2 = v[2 * t + 1];
        float recv = __shfl_xor(bit ? a : b2, 1 << s);
        v[t] = (bit ? b2 : a) + recv;
      }
    }
  }
  v[0] += __shfl_xor(v[0], 8);   // complete the 16-lane column sum
  if ((lane & 8) == 0) {
    int j   = lane & 7;          // m = j>>2, r = j&3
    int sub = lane >> 4;         // 0..3
    int row = bm * BM + wr * 32 + (j >> 2) * 16 + sub * 4 + (j & 3);
    partial[(size_t)row * NCHUNK + ((bnr << 1) | wch)] = v[0];
  }
}

// ---------------- Kernel C: per-row finish: log(sum) - exact diag ----------
// one thread per row: 32 partials = 8 x float4.
__global__ void row_finish(const float* __restrict__ partial,
                           const float* __restrict__ dlog,
                           float* __restrict__ rowloss) {
  int row = blockIdx.x * 256 + threadIdx.x;
  const float4* p = reinterpret_cast<const float4*>(partial + (size_t)row * NCHUNK);
  float s = 0.f;
#pragma unroll
  for (int q = 0; q < 8; ++q) {
    float4 pq = p[q];
    s += (pq.x + pq.y) + (pq.z + pq.w);
  }
  rowloss[row] = logf(s) - dlog[row];
}

// ---------------- Kernel D: mean over rows -> d_out[0] ----------------
__global__ void final_reduce(const float* __restrict__ rl, float* __restrict__ out) {
  __shared__ float sm[16];
  float s = 0.f;
  for (int i = threadIdx.x; i < BROWS; i += 1024) s += rl[i];
#pragma unroll
  for (int m = 1; m < 64; m <<= 1) s += __shfl_xor(s, m);
  int wid = threadIdx.x >> 6, lane = threadIdx.x & 63;
  if (lane == 0) sm[wid] = s;
  __syncthreads();
  if (wid == 0) {
    float v = (lane < 16) ? sm[lane] : 0.f;
#pragma unroll
    for (int m = 1; m < 16; m <<= 1) v += __shfl_xor(v, m);
    if (lane == 0) out[0] = v / (float)BROWS;
  }
}

extern "C" void kernel_launch(void* const* d_in, const int* in_sizes, int n_in,
                              void* d_out, int out_size, void* d_ws, size_t ws_size,
                              hipStream_t stream) {
  const float* outputs = (const float*)d_in[0];
  const float* targets = (const float*)d_in[1];
  float* out = (float*)d_out;
  char* ws = (char*)d_ws;

  uchar* o4      = (uchar*)ws;                                      // 2 MB (tiled fp4)
  uchar* t4      = (uchar*)(ws + (size_t)2 * 1024 * 1024);          // 2 MB (tiled fp4)
  float* partial = (float*)(ws + (size_t)4 * 1024 * 1024);          // 2 MB
  float* dlog    = (float*)(ws + (size_t)6 * 1024 * 1024);          // 64 KB
  float* rowloss = (float*)(ws + (size_t)6 * 1024 * 1024 + 65536);  // 64 KB

  normalize_both<<<BROWS / 4, 256, 0, stream>>>(outputs, targets, o4, t4, dlog);
  gemm_expsum<<<NBM * NBNR, 512, 0, stream>>>(o4, t4, partial);
  row_finish<<<BROWS / 256, 256, 0, stream>>>(partial, dlog, rowloss);
  final_reduce<<<1, 1024, 0, stream>>>(rowloss, out);
}